// Round 2
// baseline (2097.334 us; speedup 1.0000x reference)
//
#include <hip/hip_runtime.h>
#include <hip/hip_bf16.h>
#include <stdint.h>

// Problem constants (S,B,H,V) = (128,32,1024,32000)
#define S_LEN 128
#define BATCH 32
#define HID   1024
#define VOC   32000
#define MROWS (S_LEN*BATCH)   // 4096

typedef __attribute__((ext_vector_type(8))) short          short8;
typedef __attribute__((ext_vector_type(4))) float          floatx4;
typedef __attribute__((ext_vector_type(4))) unsigned short ushort4v;

// ---------- helpers ----------

__device__ __forceinline__ unsigned short f2bf(float f) {
  union { float f; unsigned int u; } v; v.f = f;
  unsigned int u = v.u;
  u += 0x7FFFu + ((u >> 16) & 1u);      // RNE
  return (unsigned short)(u >> 16);
}

__device__ __forceinline__ void gl_lds16(const void* g, void* l) {
  __builtin_amdgcn_global_load_lds(
      (const __attribute__((address_space(1))) void*)g,
      (__attribute__((address_space(3))) void*)l,
      16, 0, 0);
}

// Grid barrier: per-step counter (no reset), agent-scope fences for cross-XCD
// visibility of c writes. Counters memset to 0 each launch.
__device__ __forceinline__ void grid_sync(int* flags, int id, int target) {
  __syncthreads();                       // all waves done (implies vmcnt/lgkm drain)
  if (threadIdx.x == 0) {
    __builtin_amdgcn_fence(__ATOMIC_RELEASE, "agent");   // writeback L2
    __hip_atomic_fetch_add(flags + id, 1, __ATOMIC_RELAXED, __HIP_MEMORY_SCOPE_AGENT);
    while (__hip_atomic_load(flags + id, __ATOMIC_RELAXED, __HIP_MEMORY_SCOPE_AGENT) < target) { }
  }
  __syncthreads();
  __builtin_amdgcn_fence(__ATOMIC_ACQUIRE, "agent");     // invalidate L1/L2
}

// ---------- small kernels ----------

__global__ void k_f32_to_bf16(const float* __restrict__ in, unsigned short* __restrict__ out, int n4) {
  int i = blockIdx.x*blockDim.x + threadIdx.x;
  int stride = gridDim.x*blockDim.x;
  for (; i < n4; i += stride) {
    floatx4 v = ((const floatx4*)in)[i];
    ushort4v o = { f2bf(v[0]), f2bf(v[1]), f2bf(v[2]), f2bf(v[3]) };
    ((ushort4v*)out)[i] = o;
  }
}

// one block per row m = s*B+b; 256 thr x float4 = 1024 cols
__global__ __launch_bounds__(256) void k_embed(const int* __restrict__ tokens,
                                               const float* __restrict__ E,
                                               float* __restrict__ xf32,
                                               unsigned short* __restrict__ xbf) {
  int m = blockIdx.x;
  int t = tokens[m];
  floatx4 v = ((const floatx4*)(E + (size_t)t*HID))[threadIdx.x];
  ((floatx4*)(xf32 + (size_t)m*HID))[threadIdx.x] = v;
  ushort4v o = { f2bf(v[0]), f2bf(v[1]), f2bf(v[2]), f2bf(v[3]) };
  ((ushort4v*)(xbf + (size_t)m*HID))[threadIdx.x] = o;
}

__global__ void k_init_c(const float* __restrict__ hidden, float* __restrict__ cf32,
                         unsigned short* __restrict__ cbf) {
  int i = blockIdx.x*blockDim.x + threadIdx.x;   // 32768 total
  float v = hidden[i];
  cf32[i] = v;
  cbf[i]  = f2bf(v);
}

__global__ void k_copy4(const float* __restrict__ src, float* __restrict__ dst) {
  int i = blockIdx.x*blockDim.x + threadIdx.x;
  ((floatx4*)dst)[i] = ((const floatx4*)src)[i];
}

// ---------- m97-style bf16 GEMM: C[m,n] = sum_k A[m,k]*B[n,k] (+bias[n]) ----------
// BM=BN=128, BK=32, 256 thr = 4 waves (2x2), acc 4x4 of 16x16x32 MFMA.
// gridDim.x = (M/128)*(N/128) (must be %8==0 for the XCD swizzle), gridDim.y selects (B0,C0)/(B1,C1).
__global__ __launch_bounds__(256) void k_gemm_bt(
    const unsigned short* __restrict__ A,
    const unsigned short* __restrict__ B0, float* __restrict__ C0,
    const unsigned short* __restrict__ B1, float* __restrict__ C1,
    const float* __restrict__ bias,
    int M, int N, int K)
{
  __shared__ unsigned short As[128*32];
  __shared__ unsigned short Bs[128*32];
  const unsigned short* Bm = blockIdx.y ? B1 : B0;
  float* C = blockIdx.y ? C1 : C0;

  const int ntile = N >> 7;
  const int nwg = (M >> 7) * ntile;
  int b = blockIdx.x;
  int swz = (b & 7)*(nwg >> 3) + (b >> 3);     // XCD-aware swizzle (nwg%8==0)
  const int bx = swz % ntile, by = swz / ntile;
  const int m0 = by << 7, n0 = bx << 7;

  const int tid  = threadIdx.x;
  const int wave = tid >> 6, lane = tid & 63;
  const int wr = wave >> 1, wc = wave & 1;
  const int lr = lane & 15, lk = (lane >> 4) << 3;

  floatx4 acc[4][4] = {};

  const int nk = K >> 5;
  for (int kt = 0; kt < nk; ++kt) {
    const int k0 = kt << 5;
#pragma unroll
    for (int h = 0; h < 2; ++h) {
      int c = h*256 + tid;
      int row = c >> 2, kc = (c & 3) << 3;
      gl_lds16(A  + (size_t)(m0+row)*K + k0 + kc, (char*)As + c*16);
      gl_lds16(Bm + (size_t)(n0+row)*K + k0 + kc, (char*)Bs + c*16);
    }
    __syncthreads();
    short8 a[4], bb[4];
#pragma unroll
    for (int i = 0; i < 4; ++i) {
      a[i]  = *(const short8*)&As[(wr*64 + i*16 + lr)*32 + lk];
      bb[i] = *(const short8*)&Bs[(wc*64 + i*16 + lr)*32 + lk];
    }
#pragma unroll
    for (int i = 0; i < 4; ++i)
#pragma unroll
      for (int j = 0; j < 4; ++j)
        acc[i][j] = __builtin_amdgcn_mfma_f32_16x16x32_bf16(a[i], bb[j], acc[i][j], 0, 0, 0);
    __syncthreads();
  }

#pragma unroll
  for (int j = 0; j < 4; ++j) {
    int col = n0 + wc*64 + j*16 + lr;
    float bv = bias ? bias[col] : 0.f;
#pragma unroll
    for (int i = 0; i < 4; ++i) {
      int rbase = m0 + wr*64 + i*16 + (lane >> 4)*4;
#pragma unroll
      for (int r = 0; r < 4; ++r) {
        float v = acc[i][j][r] + bv;
        __builtin_nontemporal_store(v, C + (size_t)(rbase + r)*N + col);
      }
    }
  }
}

// ---------- persistent recurrence ----------
// 64 WGs x 256 thr. WG owns 16 gate-columns (n0=wg*16), both gates.
// wave = (g, mi): g = gate (ic/fc), mi = m-halftile. Full K in registers (32 frags).
// c_prev (bf16, [32][1024]) staged to LDS each step, XOR-swizzled (^((row&7)<<4))
// via pre-swizzled global source. Double-buffered c; 1 grid barrier per step.
__global__ __launch_bounds__(256) void k_rec(
    const unsigned short* __restrict__ Wic, const unsigned short* __restrict__ Wfc,
    const float* __restrict__ xi, const float* __restrict__ xf, const float* __restrict__ xv,
    const float* __restrict__ b_i, const float* __restrict__ b_f,
    float* __restrict__ cf32, unsigned short* __restrict__ cbf,
    unsigned short* __restrict__ outbf, int* __restrict__ flags)
{
  __shared__ unsigned short cs[BATCH*HID];   // 64 KB
  __shared__ float pre[2][512];              // preact [gate][row*16+col], 4 KB

  const int tid  = threadIdx.x;
  const int wave = tid >> 6, lane = tid & 63;
  const int g = wave >> 1, mi = wave & 1;
  const int n0 = blockIdx.x << 4;
  const int lr = lane & 15, lk = (lane >> 4) << 3;

  // Weights for this wave's 16 columns, full K: 32 frags = 128 VGPRs (static idx).
  const unsigned short* W = g ? Wfc : Wic;
  short8 wfrag[32];
  {
    const unsigned short* wrow = W + (size_t)(n0 + lr)*HID + lk;
#pragma unroll
    for (int kk = 0; kk < 32; ++kk)
      wfrag[kk] = *(const short8*)(wrow + kk*32);
  }

  for (int s = 0; s < S_LEN; ++s) {
    const int p = s & 1, q = p ^ 1;
    // stage c_prev -> LDS (linear dest, inverse-swizzled source)
    {
      const char* src = (const char*)(cbf + p*(BATCH*HID));
#pragma unroll
      for (int t = 0; t < 16; ++t) {
        int o = (t*256 + tid)*16;          // linear LDS byte offset
        int row = o >> 11;                 // 2048 B per row
        gl_lds16(src + (o ^ ((row & 7) << 4)), (char*)cs + o);
      }
    }
    __syncthreads();
    // preact[g][mi*16.., n0..n0+15] = c_prev . W^T (bf16 MFMA, f32 acc)
    floatx4 acc = {0.f, 0.f, 0.f, 0.f};
    {
      const int row = mi*16 + lr;
      const int rb = row*2048 + ((lane >> 4) << 4);
      const int sw = (row & 7) << 4;
#pragma unroll
      for (int kk = 0; kk < 32; ++kk) {
        short8 a = *(const short8*)((const char*)cs + ((rb + kk*64) ^ sw));
        acc = __builtin_amdgcn_mfma_f32_16x16x32_bf16(a, wfrag[kk], acc, 0, 0, 0);
      }
    }
#pragma unroll
    for (int r = 0; r < 4; ++r) {
      int row = mi*16 + (lane >> 4)*4 + r;   // D layout: col=lane&15, row=(lane>>4)*4+r
      pre[g][row*16 + lr] = acc[r];
    }
    __syncthreads();
    // gate + update for this WG's 16 columns, all 32 rows (512 cells, 2/thread)
#pragma unroll
    for (int u = 0; u < 2; ++u) {
      int cell = u*256 + tid;
      int row = cell >> 4, col = cell & 15;
      int gc = n0 + col;
      size_t idx = (size_t)s*(BATCH*HID) + (size_t)row*HID + gc;
      float zi = pre[0][cell] + xi[idx] + b_i[gc];
      float zf = pre[1][cell] + xf[idx] + b_f[gc];
      float ig = 1.f/(1.f + __expf(-zi));
      float fg = 1.f/(1.f + __expf(-zf));
      float cn = ig*xv[idx] + fg*cf32[p*(BATCH*HID) + row*HID + gc];
      cf32[q*(BATCH*HID) + row*HID + gc] = cn;
      unsigned short cb = f2bf(cn);
      cbf[q*(BATCH*HID) + row*HID + gc] = cb;
      outbf[idx] = cb;
    }
    if (s < S_LEN-1) grid_sync(flags, s, (int)gridDim.x);
  }
}

// ---------- launch ----------

extern "C" void kernel_launch(void* const* d_in, const int* in_sizes, int n_in,
                              void* d_out, int out_size, void* d_ws, size_t ws_size,
                              hipStream_t stream) {
  const int*   tokens = (const int*)  d_in[0];
  const float* hidden = (const float*)d_in[1];
  const float* E      = (const float*)d_in[2];
  const float* w_ic   = (const float*)d_in[3];
  const float* w_ix   = (const float*)d_in[4];
  const float* w_fc   = (const float*)d_in[5];
  const float* w_fx   = (const float*)d_in[6];
  const float* b_i    = (const float*)d_in[7];
  const float* b_f    = (const float*)d_in[8];
  const float* b_dec  = (const float*)d_in[9];
  float* out = (float*)d_out;

  char* ws = (char*)d_ws;
  size_t off = 0;
  auto alloc = [&](size_t bytes) -> char* {
    char* p = ws + off; off += (bytes + 255) & ~(size_t)255; return p;
  };
  unsigned short* E_bf   = (unsigned short*)alloc((size_t)VOC*HID*2);
  unsigned short* wic_bf = (unsigned short*)alloc((size_t)HID*HID*2);
  unsigned short* wix_bf = (unsigned short*)alloc((size_t)HID*HID*2);
  unsigned short* wfc_bf = (unsigned short*)alloc((size_t)HID*HID*2);
  unsigned short* wfx_bf = (unsigned short*)alloc((size_t)HID*HID*2);
  float*          x_f32  = (float*)         alloc((size_t)MROWS*HID*4);
  unsigned short* x_bf   = (unsigned short*)alloc((size_t)MROWS*HID*2);
  float*          xi     = (float*)         alloc((size_t)MROWS*HID*4);
  float*          xf     = (float*)         alloc((size_t)MROWS*HID*4);
  unsigned short* outbf  = (unsigned short*)alloc((size_t)MROWS*HID*2);
  float*          cf32   = (float*)         alloc((size_t)2*BATCH*HID*4);
  unsigned short* cbf    = (unsigned short*)alloc((size_t)2*BATCH*HID*2);
  int*            flags  = (int*)           alloc(512);

  // dtype conversions
  k_f32_to_bf16<<<2048, 256, 0, stream>>>(E,    E_bf,   VOC*HID/4);
  k_f32_to_bf16<<<512,  256, 0, stream>>>(w_ic, wic_bf, HID*HID/4);
  k_f32_to_bf16<<<512,  256, 0, stream>>>(w_ix, wix_bf, HID*HID/4);
  k_f32_to_bf16<<<512,  256, 0, stream>>>(w_fc, wfc_bf, HID*HID/4);
  k_f32_to_bf16<<<512,  256, 0, stream>>>(w_fx, wfx_bf, HID*HID/4);
  // embedding + init state + barrier counters
  k_embed<<<MROWS, 256, 0, stream>>>(tokens, E, x_f32, x_bf);
  k_init_c<<<(BATCH*HID)/256, 256, 0, stream>>>(hidden, cf32, cbf);
  hipMemsetAsync(flags, 0, 512, stream);
  // xi = x.w_ix^T, xf = x.w_fx^T  (one launch, gridDim.y = gate)
  k_gemm_bt<<<dim3(256, 2), 256, 0, stream>>>(x_bf, wix_bf, xi, wfx_bf, xf,
                                              nullptr, MROWS, HID, HID);
  // sequential scan
  k_rec<<<64, 256, 0, stream>>>(wic_bf, wfc_bf, xi, xf, x_f32, b_i, b_f,
                                cf32, cbf, outbf, flags);
  // decoder: decoded = out.E^T + b_dec
  k_gemm_bt<<<dim3(8000, 1), 256, 0, stream>>>(outbf, E_bf, out, nullptr, nullptr,
                                               b_dec, MROWS, VOC, HID);
  // hT (final state lives in cf32 buffer 0 after 128 steps)
  k_copy4<<<(BATCH*HID)/1024, 256, 0, stream>>>(cf32, out + (size_t)MROWS*VOC);
}